// Round 13
// baseline (636.468 us; speedup 1.0000x reference)
//
#include <hip/hip_runtime.h>
#include <hip/hip_bf16.h>

#define TT 256
#define NB 16
#define NTHR 768

typedef float f32x4 __attribute__((ext_vector_type(4)));
typedef _Float16 f16x8 __attribute__((ext_vector_type(8)));
typedef __fp16 fp16x2 __attribute__((ext_vector_type(2)));

// ---------------- LDS layout (bytes) ----------------
#define XPAN  0         // 4 KB: x [2 buf][16r x 128B] f16 hi, XOR-swizzled
#define H1PAN 4096      // 8 KB: h1 [2 buf][16r x 256B] f16, XOR-swizzled
#define H2PAN 12288     // 8 KB: h2 same
#define H2F32 20480     // 6 KB: final h2 f32 [u*16+r]
#define FCZ   26624     // 12 KB: FC scratch
#define LDSZ  38912

__device__ __forceinline__ float vexp2(float x) { float r; asm("v_exp_f32 %0, %1" : "=v"(r) : "v"(x)); return r; }
__device__ __forceinline__ float vrcp(float x)  { float r; asm("v_rcp_f32 %0, %1" : "=v"(r) : "v"(x)); return r; }
#define L2E 1.44269504f

#define MFMA16(a, b, c) __builtin_amdgcn_mfma_f32_16x16x32_f16(a, b, c, 0, 0, 0)

__device__ __forceinline__ unsigned short f2h_bits(float f) {
    union { _Float16 h; unsigned short u; } cv; cv.h = (_Float16)f; return cv.u;
}

union PK8 { f16x8 v8; fp16x2 v2[4]; };
__device__ __forceinline__ f16x8 pack8(const f32x4& a, const f32x4& b) {
    PK8 U;
    U.v2[0] = __builtin_amdgcn_cvt_pkrtz(a[0], a[1]);
    U.v2[1] = __builtin_amdgcn_cvt_pkrtz(a[2], a[3]);
    U.v2[2] = __builtin_amdgcn_cvt_pkrtz(b[0], b[1]);
    U.v2[3] = __builtin_amdgcn_cvt_pkrtz(b[2], b[3]);
    return U.v8;
}

// ---------------- prep16: all f16 weight fragments (verified r8-r12) ----------------
// Block layout: elem e: i=e&7, col=(e>>3)&15, kg=e>>7;
// k = ks*32+kg*8+i; unit = nt*16+col. Lane l reads [l*8 .. l*8+8) -> B-frag.
// slots: L0-x: ks*24+nt (ks 0..1, Wih0); L0-h: 48 + j*24+nt (j 0..2, Whh0);
//        L1:   120 + j*24+nt (j 0..5, Wih1|Whh1)
__global__ void prep_frags16(const float* __restrict__ Wih0, const float* __restrict__ Whh0,
                             const float* __restrict__ Wih1, const float* __restrict__ Whh1,
                             unsigned short* __restrict__ wsf2) {
    int s = blockIdx.x;        // 0..263
    int e = threadIdx.x;       // 0..511
    int i = e & 7, col = (e >> 3) & 15, kg = e >> 7;
    float wv;
    if (s < 48) {
        int ks = s / 24, nt = s % 24;
        int k = ks * 32 + kg * 8 + i, cg = nt * 16 + col;
        wv = Wih0[cg * 64 + k];
    } else if (s < 120) {
        int j = (s - 48) / 24, nt = (s - 48) % 24;
        int k = j * 32 + kg * 8 + i, cg = nt * 16 + col;
        wv = Whh0[cg * 96 + k];
    } else {
        int s2 = s - 120;
        int j = s2 / 24, nt = s2 % 24;
        int k = j * 32 + kg * 8 + i, cg = nt * 16 + col;
        wv = (k < 96) ? Wih1[cg * 96 + k] : Whh1[cg * 96 + (k - 96)];
    }
    wsf2[s * 512 + e] = f2h_bits(wv);
}

// ---------------- main: 12 waves (6 L0 + 6 L1), split-chain MFMA, batched ds_reads ----------------
__global__ __launch_bounds__(NTHR, 3) void lstm_main(
    const float* __restrict__ x,
    const float* __restrict__ b0, const float* __restrict__ b1,
    const float* __restrict__ fcW1, const float* __restrict__ fcb1,
    const float* __restrict__ fcW2, const float* __restrict__ fcb2,
    const float* __restrict__ fcW3, const float* __restrict__ fcb3,
    const unsigned short* __restrict__ wsf2,
    float* __restrict__ out)
{
    __shared__ __align__(16) char LDS[LDSZ];

    const int tid = threadIdx.x;
    const int lane = tid & 63;
    const int w = tid >> 6;                  // 0..11
    const int isB = (w ^ (w >> 2)) & 1;      // engine: 0=L0 {0,2,5,7,8,10}, 1=L1
    const int ub = w >> 1;                   // unit block 0..5
    const int l15 = lane & 15, kg = lane >> 4, r7 = l15 & 7;
    const int blk = blockIdx.x;
    const float* xblk = x + (size_t)blk * NB * TT * 64;

    // zero h panels (16 KB)
    #pragma unroll 1
    for (int i = tid; i < 4096; i += NTHR) ((int*)(LDS + H1PAN))[i] = 0;

    const int cb = ub * 2 + (l15 >> 3);      // h-write chunk base
    const int lo2 = (l15 & 7) * 2;

    // x staging: waves 0..3 (two per engine) x 32 lanes -> 128 chunks of 8 f32
    const bool stg = (w < 4) && (lane < 32);
    const int st = w * 32 + lane;            // 0..127
    const int sr = st >> 3, su = st & 7;
    const float* xsrc = xblk + (size_t)sr * TT * 64 + su * 8;
    const int xoff = sr * 128 + ((su ^ (sr & 7)) << 4);
    f32x4 xa, xb;

    // stage x(0) into XPAN buf 0
    if (stg) {
        xa = *(const f32x4*)xsrc; xb = *(const f32x4*)(xsrc + 4);
        *(f16x8*)(LDS + XPAN + xoff) = pack8(xa, xb);
    }

    // precomputed A-frag byte offsets
    const int xo0 = l15 * 128 + (((0 + kg) ^ r7) << 4);
    const int xo1 = l15 * 128 + (((4 + kg) ^ r7) << 4);
    const int ho0 = l15 * 256 + (((0 + kg) ^ r7) << 4);
    const int ho1 = l15 * 256 + (((4 + kg) ^ r7) << 4);
    const int ho2 = l15 * 256 + (((8 + kg) ^ r7) << 4);

    if (!isB) {
        // ================= L0 engine =================
        f16x8 F0x[4][2], F0h[4][3];
        #pragma unroll
        for (int g = 0; g < 4; ++g) {
            #pragma unroll
            for (int ks = 0; ks < 2; ++ks)
                F0x[g][ks] = *(const f16x8*)(wsf2 + (ks * 24 + g * 6 + ub) * 512 + lane * 8);
            #pragma unroll
            for (int j = 0; j < 3; ++j)
                F0h[g][j] = *(const f16x8*)(wsf2 + (48 + j * 24 + g * 6 + ub) * 512 + lane * 8);
        }
        float bias[4];
        #pragma unroll
        for (int g = 0; g < 4; ++g) bias[g] = b0[g * 96 + ub * 16 + l15];

        f32x4 c1 = {0.f, 0.f, 0.f, 0.f};
        __syncthreads();

        #pragma unroll 1
        for (int s = 0; s <= TT; ++s) {
            if (stg && s + 1 < TT) {   // issue x(s+1) loads early (T14)
                const float* xp = xsrc + (size_t)(s + 1) * 64;
                xa = *(const f32x4*)xp; xb = *(const f32x4*)(xp + 4);
            }
            if (s < TT) {
                const char* xr  = LDS + XPAN + ((s & 1) << 11);
                const char* h1r = LDS + H1PAN + (((s & 1) ^ 1) << 12);
                // batched A-frag loads (one lgkm wait for all 5)
                f16x8 Ax0 = *(const f16x8*)(xr + xo0);
                f16x8 Ax1 = *(const f16x8*)(xr + xo1);
                f16x8 Ah0 = *(const f16x8*)(h1r + ho0);
                f16x8 Ah1 = *(const f16x8*)(h1r + ho1);
                f16x8 Ah2 = *(const f16x8*)(h1r + ho2);
                f32x4 aA[4], aB[4];
                #pragma unroll
                for (int g = 0; g < 4; ++g) {
                    aA[g] = (f32x4){bias[g], bias[g], bias[g], bias[g]};
                    aB[g] = (f32x4){0.f, 0.f, 0.f, 0.f};
                }
                __builtin_amdgcn_s_setprio(1);
                #pragma unroll
                for (int g = 0; g < 4; ++g) aA[g] = MFMA16(Ax0, F0x[g][0], aA[g]);
                #pragma unroll
                for (int g = 0; g < 4; ++g) aB[g] = MFMA16(Ax1, F0x[g][1], aB[g]);
                #pragma unroll
                for (int g = 0; g < 4; ++g) aA[g] = MFMA16(Ah0, F0h[g][0], aA[g]);
                #pragma unroll
                for (int g = 0; g < 4; ++g) aB[g] = MFMA16(Ah1, F0h[g][1], aB[g]);
                #pragma unroll
                for (int g = 0; g < 4; ++g) aA[g] = MFMA16(Ah2, F0h[g][2], aA[g]);
                __builtin_amdgcn_s_setprio(0);
                // in-register EW (merged-rcp) -> h1(s)
                char* h1w = LDS + H1PAN + ((s & 1) << 12);
                #pragma unroll
                for (int q = 0; q < 4; ++q) {
                    float ei = vexp2((aA[0][q] + aB[0][q]) * (-L2E));
                    float ef = vexp2((aA[1][q] + aB[1][q]) * (-L2E));
                    float eg = vexp2((aA[2][q] + aB[2][q]) * (-2.f * L2E));
                    float eo = vexp2((aA[3][q] + aB[3][q]) * (-L2E));
                    float ivgv = (1.f - eg) * vrcp((1.f + ei) * (1.f + eg));
                    float fv = vrcp(1.f + ef);
                    float cn = fmaf(fv, c1[q], ivgv);
                    c1[q] = cn;
                    float ec = vexp2(cn * (-2.f * L2E));
                    float h = (1.f - ec) * vrcp((1.f + eo) * (1.f + ec));
                    int r_ = kg * 4 + q;
                    int off = r_ * 256 + ((cb ^ (r_ & 7)) << 4) + lo2;
                    *(unsigned short*)(h1w + off) = f2h_bits(h);
                }
            }
            // write staged x(s+1)
            if (stg && s + 1 < TT)
                *(f16x8*)(LDS + XPAN + (((s + 1) & 1) << 11) + xoff) = pack8(xa, xb);
            __syncthreads();
        }
    } else {
        // ================= L1 engine =================
        f16x8 F1[4][6];
        #pragma unroll
        for (int g = 0; g < 4; ++g)
            #pragma unroll
            for (int j = 0; j < 6; ++j)
                F1[g][j] = *(const f16x8*)(wsf2 + (120 + j * 24 + g * 6 + ub) * 512 + lane * 8);
        float bias[4];
        #pragma unroll
        for (int g = 0; g < 4; ++g) bias[g] = b1[g * 96 + ub * 16 + l15];

        f32x4 c2 = {0.f, 0.f, 0.f, 0.f};
        __syncthreads();

        #pragma unroll 1
        for (int s = 0; s <= TT; ++s) {
            if (stg && s + 1 < TT) {   // issue x(s+1) loads early
                const float* xp = xsrc + (size_t)(s + 1) * 64;
                xa = *(const f32x4*)xp; xb = *(const f32x4*)(xp + 4);
            }
            if (s >= 1) {
                const char* h1r = LDS + H1PAN + (((s & 1) ^ 1) << 12);   // h1(s-1)
                const char* h2r = LDS + H2PAN + ((s & 1) << 12);         // h2(s-2)
                // batched A-frag loads
                f16x8 A0 = *(const f16x8*)(h1r + ho0);
                f16x8 A1 = *(const f16x8*)(h1r + ho1);
                f16x8 A2 = *(const f16x8*)(h1r + ho2);
                f16x8 A3 = *(const f16x8*)(h2r + ho0);
                f16x8 A4 = *(const f16x8*)(h2r + ho1);
                f16x8 A5 = *(const f16x8*)(h2r + ho2);
                f32x4 aA[4], aB[4];
                #pragma unroll
                for (int g = 0; g < 4; ++g) {
                    aA[g] = (f32x4){bias[g], bias[g], bias[g], bias[g]};
                    aB[g] = (f32x4){0.f, 0.f, 0.f, 0.f};
                }
                __builtin_amdgcn_s_setprio(1);
                #pragma unroll
                for (int g = 0; g < 4; ++g) aA[g] = MFMA16(A0, F1[g][0], aA[g]);
                #pragma unroll
                for (int g = 0; g < 4; ++g) aB[g] = MFMA16(A1, F1[g][1], aB[g]);
                #pragma unroll
                for (int g = 0; g < 4; ++g) aA[g] = MFMA16(A2, F1[g][2], aA[g]);
                #pragma unroll
                for (int g = 0; g < 4; ++g) aB[g] = MFMA16(A3, F1[g][3], aB[g]);
                #pragma unroll
                for (int g = 0; g < 4; ++g) aA[g] = MFMA16(A4, F1[g][4], aA[g]);
                #pragma unroll
                for (int g = 0; g < 4; ++g) aB[g] = MFMA16(A5, F1[g][5], aB[g]);
                __builtin_amdgcn_s_setprio(0);
                // in-register EW (merged-rcp) -> h2(s-1)
                char* h2w = LDS + H2PAN + ((~s & 1) << 12);
                #pragma unroll
                for (int q = 0; q < 4; ++q) {
                    float ei = vexp2((aA[0][q] + aB[0][q]) * (-L2E));
                    float ef = vexp2((aA[1][q] + aB[1][q]) * (-L2E));
                    float eg = vexp2((aA[2][q] + aB[2][q]) * (-2.f * L2E));
                    float eo = vexp2((aA[3][q] + aB[3][q]) * (-L2E));
                    float ivgv = (1.f - eg) * vrcp((1.f + ei) * (1.f + eg));
                    float fv = vrcp(1.f + ef);
                    float cn = fmaf(fv, c2[q], ivgv);
                    c2[q] = cn;
                    float ec = vexp2(cn * (-2.f * L2E));
                    float h = (1.f - ec) * vrcp((1.f + eo) * (1.f + ec));
                    int r_ = kg * 4 + q;
                    int off = r_ * 256 + ((cb ^ (r_ & 7)) << 4) + lo2;
                    *(unsigned short*)(h2w + off) = f2h_bits(h);
                    if (s == TT)
                        ((float*)(LDS + H2F32))[(ub * 16 + l15) * 16 + r_] = h;
                }
            }
            // write staged x(s+1)
            if (stg && s + 1 < TT)
                *(f16x8*)(LDS + XPAN + (((s + 1) & 1) << 11) + xoff) = pack8(xa, xb);
            __syncthreads();
        }
    }
    __syncthreads();

    // ---------------- MLP head on f32 h2(T-1): h2f[u*16 + r] ----------------
    const float* h2f = (const float*)(LDS + H2F32);
    float* z1 = (float*)(LDS + FCZ);          // [16][96]
    float* z2 = z1 + 1536;
    if (tid < 192) {
        int u = tid % 96, half = tid / 96;
        float s0 = fcb1[u];
        for (int r = half * 8; r < half * 8 + 8; ++r) {
            float s = s0;
            #pragma unroll 4
            for (int k = 0; k < 96; ++k) s += fcW1[u * 96 + k] * h2f[k * 16 + r];
            z1[r * 96 + u] = s > 0.f ? s : 0.01f * s;
        }
    }
    __syncthreads();
    if (tid < 192) {
        int u = tid % 96, half = tid / 96;
        float s0 = fcb2[u];
        for (int r = half * 8; r < half * 8 + 8; ++r) {
            float s = s0;
            #pragma unroll 4
            for (int k = 0; k < 96; ++k) s += fcW2[u * 96 + k] * z1[r * 96 + k];
            z2[r * 96 + u] = s > 0.f ? s : 0.01f * s;
        }
    }
    __syncthreads();
    if (tid < NB) {
        float s = fcb3[0];
        #pragma unroll 4
        for (int k = 0; k < 96; ++k) s += fcW3[k] * z2[tid * 96 + k];
        out[blk * NB + tid] = s;
    }
}

extern "C" void kernel_launch(void* const* d_in, const int* in_sizes, int n_in,
                              void* d_out, int out_size, void* d_ws, size_t ws_size,
                              hipStream_t stream) {
    const float* x    = (const float*)d_in[0];
    const float* Wih0 = (const float*)d_in[1];
    const float* Whh0 = (const float*)d_in[2];
    const float* b0   = (const float*)d_in[3];
    const float* Wih1 = (const float*)d_in[4];
    const float* Whh1 = (const float*)d_in[5];
    const float* b1   = (const float*)d_in[6];
    const float* fcW1 = (const float*)d_in[7];
    const float* fcb1 = (const float*)d_in[8];
    const float* fcW2 = (const float*)d_in[9];
    const float* fcb2 = (const float*)d_in[10];
    const float* fcW3 = (const float*)d_in[11];
    const float* fcb3 = (const float*)d_in[12];

    unsigned short* wsf2 = (unsigned short*)d_ws;   // 264 KB f16 fragment blocks

    prep_frags16<<<264, 512, 0, stream>>>(Wih0, Whh0, Wih1, Whh1, wsf2);
    lstm_main<<<256, NTHR, 0, stream>>>(x, b0, b1, fcW1, fcb1, fcW2, fcb2,
                                        fcW3, fcb3, wsf2, (float*)d_out);
}

// Round 14
// 562.116 us; speedup vs baseline: 1.1323x; 1.1323x over previous
//
#include <hip/hip_runtime.h>
#include <hip/hip_bf16.h>

#define TT 256
#define NB 16
#define NTHR 768

typedef float f32x4 __attribute__((ext_vector_type(4)));
typedef _Float16 f16x8 __attribute__((ext_vector_type(8)));
typedef __fp16 fp16x2 __attribute__((ext_vector_type(2)));

// ---------------- LDS layout (bytes) ----------------
#define XPAN  0         // 4 KB: x [2 buf][16r x 128B] f16 hi, XOR-swizzled
#define H1PAN 4096      // 8 KB: h1 [2 buf][16r x 256B] f16, XOR-swizzled
#define H2PAN 12288     // 8 KB: h2 same
#define H2F32 20480     // 6 KB: final h2 f32 [u*16+r]
#define FCZ   26624     // 12 KB: FC scratch
#define LDSZ  38912

__device__ __forceinline__ float vexp2(float x) { float r; asm("v_exp_f32 %0, %1" : "=v"(r) : "v"(x)); return r; }
__device__ __forceinline__ float vrcp(float x)  { float r; asm("v_rcp_f32 %0, %1" : "=v"(r) : "v"(x)); return r; }
#define L2E 1.44269504f

#define MFMA16(a, b, c) __builtin_amdgcn_mfma_f32_16x16x32_f16(a, b, c, 0, 0, 0)

__device__ __forceinline__ unsigned short f2h_bits(float f) {
    union { _Float16 h; unsigned short u; } cv; cv.h = (_Float16)f; return cv.u;
}

union PK8 { f16x8 v8; fp16x2 v2[4]; };
__device__ __forceinline__ f16x8 pack8(const f32x4& a, const f32x4& b) {
    PK8 U;
    U.v2[0] = __builtin_amdgcn_cvt_pkrtz(a[0], a[1]);
    U.v2[1] = __builtin_amdgcn_cvt_pkrtz(a[2], a[3]);
    U.v2[2] = __builtin_amdgcn_cvt_pkrtz(b[0], b[1]);
    U.v2[3] = __builtin_amdgcn_cvt_pkrtz(b[2], b[3]);
    return U.v8;
}

// ---------------- prep16: all f16 weight fragments (verified r8-r12) ----------------
// Block layout: elem e: i=e&7, col=(e>>3)&15, kg=e>>7;
// k = ks*32+kg*8+i; unit = nt*16+col. Lane l reads [l*8 .. l*8+8) -> B-frag.
// slots: L0-x: ks*24+nt (ks 0..1, Wih0); L0-h: 48 + j*24+nt (j 0..2, Whh0);
//        L1:   120 + j*24+nt (j 0..5, Wih1|Whh1)
__global__ void prep_frags16(const float* __restrict__ Wih0, const float* __restrict__ Whh0,
                             const float* __restrict__ Wih1, const float* __restrict__ Whh1,
                             unsigned short* __restrict__ wsf2) {
    int s = blockIdx.x;        // 0..263
    int e = threadIdx.x;       // 0..511
    int i = e & 7, col = (e >> 3) & 15, kg = e >> 7;
    float wv;
    if (s < 48) {
        int ks = s / 24, nt = s % 24;
        int k = ks * 32 + kg * 8 + i, cg = nt * 16 + col;
        wv = Wih0[cg * 64 + k];
    } else if (s < 120) {
        int j = (s - 48) / 24, nt = (s - 48) % 24;
        int k = j * 32 + kg * 8 + i, cg = nt * 16 + col;
        wv = Whh0[cg * 96 + k];
    } else {
        int s2 = s - 120;
        int j = s2 / 24, nt = s2 % 24;
        int k = j * 32 + kg * 8 + i, cg = nt * 16 + col;
        wv = (k < 96) ? Wih1[cg * 96 + k] : Whh1[cg * 96 + (k - 96)];
    }
    wsf2[s * 512 + e] = f2h_bits(wv);
}

// ---------------- main: 12 waves (6 L0 + 6 L1), acc-split (isolated), interleaved ds_reads ----------------
__global__ __launch_bounds__(NTHR, 3) void lstm_main(
    const float* __restrict__ x,
    const float* __restrict__ b0, const float* __restrict__ b1,
    const float* __restrict__ fcW1, const float* __restrict__ fcb1,
    const float* __restrict__ fcW2, const float* __restrict__ fcb2,
    const float* __restrict__ fcW3, const float* __restrict__ fcb3,
    const unsigned short* __restrict__ wsf2,
    float* __restrict__ out)
{
    __shared__ __align__(16) char LDS[LDSZ];

    const int tid = threadIdx.x;
    const int lane = tid & 63;
    const int w = tid >> 6;                  // 0..11
    const int isB = (w ^ (w >> 2)) & 1;      // engine: 0=L0 {0,2,5,7,8,10}, 1=L1
    const int ub = w >> 1;                   // unit block 0..5
    const int l15 = lane & 15, kg = lane >> 4, r7 = l15 & 7;
    const int blk = blockIdx.x;
    const float* xblk = x + (size_t)blk * NB * TT * 64;

    // zero h panels (16 KB)
    #pragma unroll 1
    for (int i = tid; i < 4096; i += NTHR) ((int*)(LDS + H1PAN))[i] = 0;

    const int cb = ub * 2 + (l15 >> 3);      // h-write chunk base
    const int lo2 = (l15 & 7) * 2;

    // x staging: waves 0..3 (two per engine) x 32 lanes -> 128 chunks of 8 f32
    const bool stg = (w < 4) && (lane < 32);
    const int st = w * 32 + lane;            // 0..127
    const int sr = st >> 3, su = st & 7;
    const float* xsrc = xblk + (size_t)sr * TT * 64 + su * 8;
    const int xoff = sr * 128 + ((su ^ (sr & 7)) << 4);
    f32x4 xa, xb;

    // stage x(0) into XPAN buf 0
    if (stg) {
        xa = *(const f32x4*)xsrc; xb = *(const f32x4*)(xsrc + 4);
        *(f16x8*)(LDS + XPAN + xoff) = pack8(xa, xb);
    }

    if (!isB) {
        // ================= L0 engine =================
        f16x8 F0x[4][2], F0h[4][3];
        #pragma unroll
        for (int g = 0; g < 4; ++g) {
            #pragma unroll
            for (int ks = 0; ks < 2; ++ks)
                F0x[g][ks] = *(const f16x8*)(wsf2 + (ks * 24 + g * 6 + ub) * 512 + lane * 8);
            #pragma unroll
            for (int j = 0; j < 3; ++j)
                F0h[g][j] = *(const f16x8*)(wsf2 + (48 + j * 24 + g * 6 + ub) * 512 + lane * 8);
        }
        float bias[4];
        #pragma unroll
        for (int g = 0; g < 4; ++g) bias[g] = b0[g * 96 + ub * 16 + l15];

        f32x4 c1 = {0.f, 0.f, 0.f, 0.f};
        __syncthreads();

        #pragma unroll 1
        for (int s = 0; s <= TT; ++s) {
            if (stg && s + 1 < TT) {   // issue x(s+1) loads early (T14)
                const float* xp = xsrc + (size_t)(s + 1) * 64;
                xa = *(const f32x4*)xp; xb = *(const f32x4*)(xp + 4);
            }
            if (s < TT) {
                const char* xr  = LDS + XPAN + ((s & 1) << 11);
                const char* h1r = LDS + H1PAN + (((s & 1) ^ 1) << 12);
                f32x4 aA[4], aB[4];
                #pragma unroll
                for (int g = 0; g < 4; ++g) {
                    aA[g] = (f32x4){bias[g], bias[g], bias[g], bias[g]};
                    aB[g] = (f32x4){0.f, 0.f, 0.f, 0.f};
                }
                __builtin_amdgcn_s_setprio(1);
                // slice 0 -> aA, slice 1 -> aB (x part)
                {
                    int off = l15 * 128 + (((0 + kg) ^ r7) << 4);
                    f16x8 xh = *(const f16x8*)(xr + off);
                    #pragma unroll
                    for (int g = 0; g < 4; ++g) aA[g] = MFMA16(xh, F0x[g][0], aA[g]);
                }
                {
                    int off = l15 * 128 + (((4 + kg) ^ r7) << 4);
                    f16x8 xh = *(const f16x8*)(xr + off);
                    #pragma unroll
                    for (int g = 0; g < 4; ++g) aB[g] = MFMA16(xh, F0x[g][1], aB[g]);
                }
                // h slices alternate aA/aB
                #pragma unroll
                for (int j = 0; j < 3; ++j) {
                    int off = l15 * 256 + (((j * 4 + kg) ^ r7) << 4);
                    f16x8 ah = *(const f16x8*)(h1r + off);
                    if (j & 1) {
                        #pragma unroll
                        for (int g = 0; g < 4; ++g) aB[g] = MFMA16(ah, F0h[g][j], aB[g]);
                    } else {
                        #pragma unroll
                        for (int g = 0; g < 4; ++g) aA[g] = MFMA16(ah, F0h[g][j], aA[g]);
                    }
                }
                __builtin_amdgcn_s_setprio(0);
                // in-register EW (merged-rcp) -> h1(s)
                char* h1w = LDS + H1PAN + ((s & 1) << 12);
                #pragma unroll
                for (int q = 0; q < 4; ++q) {
                    float ei = vexp2((aA[0][q] + aB[0][q]) * (-L2E));
                    float ef = vexp2((aA[1][q] + aB[1][q]) * (-L2E));
                    float eg = vexp2((aA[2][q] + aB[2][q]) * (-2.f * L2E));
                    float eo = vexp2((aA[3][q] + aB[3][q]) * (-L2E));
                    float ivgv = (1.f - eg) * vrcp((1.f + ei) * (1.f + eg));
                    float fv = vrcp(1.f + ef);
                    float cn = fmaf(fv, c1[q], ivgv);
                    c1[q] = cn;
                    float ec = vexp2(cn * (-2.f * L2E));
                    float h = (1.f - ec) * vrcp((1.f + eo) * (1.f + ec));
                    int r_ = kg * 4 + q;
                    int off = r_ * 256 + ((cb ^ (r_ & 7)) << 4) + lo2;
                    *(unsigned short*)(h1w + off) = f2h_bits(h);
                }
            }
            // write staged x(s+1)
            if (stg && s + 1 < TT)
                *(f16x8*)(LDS + XPAN + (((s + 1) & 1) << 11) + xoff) = pack8(xa, xb);
            __syncthreads();
        }
    } else {
        // ================= L1 engine =================
        f16x8 F1[4][6];
        #pragma unroll
        for (int g = 0; g < 4; ++g)
            #pragma unroll
            for (int j = 0; j < 6; ++j)
                F1[g][j] = *(const f16x8*)(wsf2 + (120 + j * 24 + g * 6 + ub) * 512 + lane * 8);
        float bias[4];
        #pragma unroll
        for (int g = 0; g < 4; ++g) bias[g] = b1[g * 96 + ub * 16 + l15];

        f32x4 c2 = {0.f, 0.f, 0.f, 0.f};
        __syncthreads();

        #pragma unroll 1
        for (int s = 0; s <= TT; ++s) {
            if (stg && s + 1 < TT) {   // issue x(s+1) loads early
                const float* xp = xsrc + (size_t)(s + 1) * 64;
                xa = *(const f32x4*)xp; xb = *(const f32x4*)(xp + 4);
            }
            if (s >= 1) {
                const char* h1r = LDS + H1PAN + (((s & 1) ^ 1) << 12);   // h1(s-1)
                const char* h2r = LDS + H2PAN + ((s & 1) << 12);         // h2(s-2)
                f32x4 aA[4], aB[4];
                #pragma unroll
                for (int g = 0; g < 4; ++g) {
                    aA[g] = (f32x4){bias[g], bias[g], bias[g], bias[g]};
                    aB[g] = (f32x4){0.f, 0.f, 0.f, 0.f};
                }
                __builtin_amdgcn_s_setprio(1);
                #pragma unroll
                for (int j = 0; j < 6; ++j) {
                    const char* pan = (j < 3) ? h1r : h2r;
                    int cc = (j < 3) ? j : j - 3;
                    int off = l15 * 256 + (((cc * 4 + kg) ^ r7) << 4);
                    f16x8 ah = *(const f16x8*)(pan + off);
                    if (j & 1) {
                        #pragma unroll
                        for (int g = 0; g < 4; ++g) aB[g] = MFMA16(ah, F1[g][j], aB[g]);
                    } else {
                        #pragma unroll
                        for (int g = 0; g < 4; ++g) aA[g] = MFMA16(ah, F1[g][j], aA[g]);
                    }
                }
                __builtin_amdgcn_s_setprio(0);
                // in-register EW (merged-rcp) -> h2(s-1)
                char* h2w = LDS + H2PAN + ((~s & 1) << 12);
                #pragma unroll
                for (int q = 0; q < 4; ++q) {
                    float ei = vexp2((aA[0][q] + aB[0][q]) * (-L2E));
                    float ef = vexp2((aA[1][q] + aB[1][q]) * (-L2E));
                    float eg = vexp2((aA[2][q] + aB[2][q]) * (-2.f * L2E));
                    float eo = vexp2((aA[3][q] + aB[3][q]) * (-L2E));
                    float ivgv = (1.f - eg) * vrcp((1.f + ei) * (1.f + eg));
                    float fv = vrcp(1.f + ef);
                    float cn = fmaf(fv, c2[q], ivgv);
                    c2[q] = cn;
                    float ec = vexp2(cn * (-2.f * L2E));
                    float h = (1.f - ec) * vrcp((1.f + eo) * (1.f + ec));
                    int r_ = kg * 4 + q;
                    int off = r_ * 256 + ((cb ^ (r_ & 7)) << 4) + lo2;
                    *(unsigned short*)(h2w + off) = f2h_bits(h);
                    if (s == TT)
                        ((float*)(LDS + H2F32))[(ub * 16 + l15) * 16 + r_] = h;
                }
            }
            // write staged x(s+1)
            if (stg && s + 1 < TT)
                *(f16x8*)(LDS + XPAN + (((s + 1) & 1) << 11) + xoff) = pack8(xa, xb);
            __syncthreads();
        }
    }
    __syncthreads();

    // ---------------- MLP head on f32 h2(T-1): h2f[u*16 + r] ----------------
    const float* h2f = (const float*)(LDS + H2F32);
    float* z1 = (float*)(LDS + FCZ);          // [16][96]
    float* z2 = z1 + 1536;
    if (tid < 192) {
        int u = tid % 96, half = tid / 96;
        float s0 = fcb1[u];
        for (int r = half * 8; r < half * 8 + 8; ++r) {
            float s = s0;
            #pragma unroll 4
            for (int k = 0; k < 96; ++k) s += fcW1[u * 96 + k] * h2f[k * 16 + r];
            z1[r * 96 + u] = s > 0.f ? s : 0.01f * s;
        }
    }
    __syncthreads();
    if (tid < 192) {
        int u = tid % 96, half = tid / 96;
        float s0 = fcb2[u];
        for (int r = half * 8; r < half * 8 + 8; ++r) {
            float s = s0;
            #pragma unroll 4
            for (int k = 0; k < 96; ++k) s += fcW2[u * 96 + k] * z1[r * 96 + k];
            z2[r * 96 + u] = s > 0.f ? s : 0.01f * s;
        }
    }
    __syncthreads();
    if (tid < NB) {
        float s = fcb3[0];
        #pragma unroll 4
        for (int k = 0; k < 96; ++k) s += fcW3[k] * z2[tid * 96 + k];
        out[blk * NB + tid] = s;
    }
}

extern "C" void kernel_launch(void* const* d_in, const int* in_sizes, int n_in,
                              void* d_out, int out_size, void* d_ws, size_t ws_size,
                              hipStream_t stream) {
    const float* x    = (const float*)d_in[0];
    const float* Wih0 = (const float*)d_in[1];
    const float* Whh0 = (const float*)d_in[2];
    const float* b0   = (const float*)d_in[3];
    const float* Wih1 = (const float*)d_in[4];
    const float* Whh1 = (const float*)d_in[5];
    const float* b1   = (const float*)d_in[6];
    const float* fcW1 = (const float*)d_in[7];
    const float* fcb1 = (const float*)d_in[8];
    const float* fcW2 = (const float*)d_in[9];
    const float* fcb2 = (const float*)d_in[10];
    const float* fcW3 = (const float*)d_in[11];
    const float* fcb3 = (const float*)d_in[12];

    unsigned short* wsf2 = (unsigned short*)d_ws;   // 264 KB f16 fragment blocks

    prep_frags16<<<264, 512, 0, stream>>>(Wih0, Whh0, Wih1, Whh1, wsf2);
    lstm_main<<<256, NTHR, 0, stream>>>(x, b0, b1, fcW1, fcb1, fcW2, fcb2,
                                        fcW3, fcb3, wsf2, (float*)d_out);
}

// Round 15
// 395.670 us; speedup vs baseline: 1.6086x; 1.4207x over previous
//
#include <hip/hip_runtime.h>
#include <hip/hip_bf16.h>

#define TT 256
#define NB 16
#define NTHR 768

typedef float f32x4 __attribute__((ext_vector_type(4)));
typedef _Float16 f16x8 __attribute__((ext_vector_type(8)));
typedef __fp16 fp16x2 __attribute__((ext_vector_type(2)));

// ---------------- LDS layout (bytes) ----------------
#define XPAN  0         // 4 KB: x [2 buf][16r x 128B] f16, XOR-swizzled
#define H1PAN 4096      // 16 KB: h1 ring [4 slots][16r x 256B] f16, XOR-swizzled
#define H2PAN 20480     // 16 KB: h2 ring [4 slots]
#define H2F32 36864     // 6 KB: final h2 f32 [u*16+r]
#define FCZ   43008     // 12 KB: FC scratch
#define CNT   55296     // counters: 0=prodH1 1=consH1 2=prodH2
#define LDSZ  55360

__device__ __forceinline__ float vexp2(float x) { float r; asm("v_exp_f32 %0, %1" : "=v"(r) : "v"(x)); return r; }
__device__ __forceinline__ float vrcp(float x)  { float r; asm("v_rcp_f32 %0, %1" : "=v"(r) : "v"(x)); return r; }
#define L2E 1.44269504f

#define MFMA16(a, b, c) __builtin_amdgcn_mfma_f32_16x16x32_f16(a, b, c, 0, 0, 0)

__device__ __forceinline__ unsigned short f2h_bits(float f) {
    union { _Float16 h; unsigned short u; } cv; cv.h = (_Float16)f; return cv.u;
}

union PK8 { f16x8 v8; fp16x2 v2[4]; };
__device__ __forceinline__ f16x8 pack8(const f32x4& a, const f32x4& b) {
    PK8 U;
    U.v2[0] = __builtin_amdgcn_cvt_pkrtz(a[0], a[1]);
    U.v2[1] = __builtin_amdgcn_cvt_pkrtz(a[2], a[3]);
    U.v2[2] = __builtin_amdgcn_cvt_pkrtz(b[0], b[1]);
    U.v2[3] = __builtin_amdgcn_cvt_pkrtz(b[2], b[3]);
    return U.v8;
}

// spin until *cnt >= target (acquire); no-op if target <= 0
__device__ __forceinline__ void spinge(int* cnt, int target) {
    if (target > 0) {
        while (__hip_atomic_load(cnt, __ATOMIC_RELAXED, __HIP_MEMORY_SCOPE_WORKGROUP) < target)
            __builtin_amdgcn_s_sleep(1);
        __threadfence_block();
    }
}
// release-fence + one increment per wave
__device__ __forceinline__ void signal(int* cnt, int lane) {
    __threadfence_block();
    if (lane == 0)
        __hip_atomic_fetch_add(cnt, 1, __ATOMIC_RELAXED, __HIP_MEMORY_SCOPE_WORKGROUP);
}

// ---------------- prep16: all f16 weight fragments (verified r8-r14) ----------------
__global__ void prep_frags16(const float* __restrict__ Wih0, const float* __restrict__ Whh0,
                             const float* __restrict__ Wih1, const float* __restrict__ Whh1,
                             unsigned short* __restrict__ wsf2) {
    int s = blockIdx.x;        // 0..263
    int e = threadIdx.x;       // 0..511
    int i = e & 7, col = (e >> 3) & 15, kg = e >> 7;
    float wv;
    if (s < 48) {
        int ks = s / 24, nt = s % 24;
        int k = ks * 32 + kg * 8 + i, cg = nt * 16 + col;
        wv = Wih0[cg * 64 + k];
    } else if (s < 120) {
        int j = (s - 48) / 24, nt = (s - 48) % 24;
        int k = j * 32 + kg * 8 + i, cg = nt * 16 + col;
        wv = Whh0[cg * 96 + k];
    } else {
        int s2 = s - 120;
        int j = s2 / 24, nt = s2 % 24;
        int k = j * 32 + kg * 8 + i, cg = nt * 16 + col;
        wv = (k < 96) ? Wih1[cg * 96 + k] : Whh1[cg * 96 + (k - 96)];
    }
    wsf2[s * 512 + e] = f2h_bits(wv);
}

// ---------------- main: decoupled engines, LDS flag sync, no per-step barrier ----------------
__global__ __launch_bounds__(NTHR, 3) void lstm_main(
    const float* __restrict__ x,
    const float* __restrict__ b0, const float* __restrict__ b1,
    const float* __restrict__ fcW1, const float* __restrict__ fcb1,
    const float* __restrict__ fcW2, const float* __restrict__ fcb2,
    const float* __restrict__ fcW3, const float* __restrict__ fcb3,
    const unsigned short* __restrict__ wsf2,
    float* __restrict__ out)
{
    __shared__ __align__(16) char LDS[LDSZ];

    const int tid = threadIdx.x;
    const int lane = tid & 63;
    const int w = tid >> 6;                  // 0..11
    const int isB = (w ^ (w >> 2)) & 1;      // engine: 0=L0 {0,2,5,7,8,10}, 1=L1
    const int ub = w >> 1;                   // unit block 0..5
    const int l15 = lane & 15, kg = lane >> 4, r7 = l15 & 7;
    const int blk = blockIdx.x;
    const float* xblk = x + (size_t)blk * NB * TT * 64;

    int* prodH1 = (int*)(LDS + CNT);
    int* consH1 = (int*)(LDS + CNT) + 1;
    int* prodH2 = (int*)(LDS + CNT) + 2;

    // zero h rings (32 KB) + counters
    #pragma unroll 1
    for (int i = tid; i < 8192; i += NTHR) ((int*)(LDS + H1PAN))[i] = 0;
    if (tid < 16) ((int*)(LDS + CNT))[tid] = 0;

    const int cb = ub * 2 + (l15 >> 3);      // h-write chunk base
    const int lo2 = (l15 & 7) * 2;

    // x staging: L0-engine waves {0,2,5,7} x 32 lanes -> 128 chunks of 8 f32
    const int sidx = (w == 0) ? 0 : (w == 2) ? 1 : (w == 5) ? 2 : 3;
    const bool stg = (w == 0 || w == 2 || w == 5 || w == 7) && (lane < 32);
    const int st = sidx * 32 + lane;         // 0..127
    const int sr = st >> 3, su = st & 7;
    const float* xsrc = xblk + (size_t)sr * TT * 64 + su * 8;
    const int xoff = sr * 128 + ((su ^ (sr & 7)) << 4);
    f32x4 xa, xb;

    // stage x(0) into XPAN buf 0
    if (stg) {
        xa = *(const f32x4*)xsrc; xb = *(const f32x4*)(xsrc + 4);
        *(f16x8*)(LDS + XPAN + xoff) = pack8(xa, xb);
    }
    __syncthreads();

    if (!isB) {
        // ================= L0 engine: free-running, gated by its own ring + L1 backpressure =================
        f16x8 F0x[4][2], F0h[4][3];
        #pragma unroll
        for (int g = 0; g < 4; ++g) {
            #pragma unroll
            for (int ks = 0; ks < 2; ++ks)
                F0x[g][ks] = *(const f16x8*)(wsf2 + (ks * 24 + g * 6 + ub) * 512 + lane * 8);
            #pragma unroll
            for (int j = 0; j < 3; ++j)
                F0h[g][j] = *(const f16x8*)(wsf2 + (48 + j * 24 + g * 6 + ub) * 512 + lane * 8);
        }
        float bias[4];
        #pragma unroll
        for (int g = 0; g < 4; ++g) bias[g] = b0[g * 96 + ub * 16 + l15];

        f32x4 c1 = {0.f, 0.f, 0.f, 0.f};

        #pragma unroll 1
        for (int s = 0; s < TT; ++s) {
            if (stg && s + 1 < TT) {     // issue x(s+1) global loads before any spin
                const float* xp = xsrc + (size_t)(s + 1) * 64;
                xa = *(const f32x4*)xp; xb = *(const f32x4*)(xp + 4);
            }
            spinge(prodH1, 6 * s);       // h1(s-1) complete (all 6 L0 waves)
            const char* xr  = LDS + XPAN + ((s & 1) << 11);
            const char* h1r = LDS + H1PAN + (((s - 1) & 3) << 12);
            f32x4 a[4];
            #pragma unroll
            for (int g = 0; g < 4; ++g) a[g] = (f32x4){bias[g], bias[g], bias[g], bias[g]};
            __builtin_amdgcn_s_setprio(1);
            #pragma unroll
            for (int ks = 0; ks < 2; ++ks) {
                int off = l15 * 128 + (((ks * 4 + kg) ^ r7) << 4);
                f16x8 xh = *(const f16x8*)(xr + off);
                #pragma unroll
                for (int g = 0; g < 4; ++g) a[g] = MFMA16(xh, F0x[g][ks], a[g]);
            }
            #pragma unroll
            for (int j = 0; j < 3; ++j) {
                int off = l15 * 256 + (((j * 4 + kg) ^ r7) << 4);
                f16x8 ah = *(const f16x8*)(h1r + off);
                #pragma unroll
                for (int g = 0; g < 4; ++g) a[g] = MFMA16(ah, F0h[g][j], a[g]);
            }
            __builtin_amdgcn_s_setprio(0);
            spinge(consH1, 6 * (s - 3)); // slot s&3 free (L1 consumed h1(s-4))
            // in-register EW (merged-rcp) -> h1(s) slot s&3
            char* h1w = LDS + H1PAN + ((s & 3) << 12);
            #pragma unroll
            for (int q = 0; q < 4; ++q) {
                float ei = vexp2(a[0][q] * (-L2E));
                float ef = vexp2(a[1][q] * (-L2E));
                float eg = vexp2(a[2][q] * (-2.f * L2E));
                float eo = vexp2(a[3][q] * (-L2E));
                float ivgv = (1.f - eg) * vrcp((1.f + ei) * (1.f + eg));
                float fv = vrcp(1.f + ef);
                float cn = fmaf(fv, c1[q], ivgv);
                c1[q] = cn;
                float ec = vexp2(cn * (-2.f * L2E));
                float h = (1.f - ec) * vrcp((1.f + eo) * (1.f + ec));
                int r_ = kg * 4 + q;
                int off = r_ * 256 + ((cb ^ (r_ & 7)) << 4) + lo2;
                *(unsigned short*)(h1w + off) = f2h_bits(h);
            }
            if (stg && s + 1 < TT)
                *(f16x8*)(LDS + XPAN + (((s + 1) & 1) << 11) + xoff) = pack8(xa, xb);
            signal(prodH1, lane);
        }
    } else {
        // ================= L1 engine: lags L0, consumes h1 ring =================
        f16x8 F1[4][6];
        #pragma unroll
        for (int g = 0; g < 4; ++g)
            #pragma unroll
            for (int j = 0; j < 6; ++j)
                F1[g][j] = *(const f16x8*)(wsf2 + (120 + j * 24 + g * 6 + ub) * 512 + lane * 8);
        float bias[4];
        #pragma unroll
        for (int g = 0; g < 4; ++g) bias[g] = b1[g * 96 + ub * 16 + l15];

        f32x4 c2 = {0.f, 0.f, 0.f, 0.f};

        #pragma unroll 1
        for (int sp = 0; sp < TT; ++sp) {
            spinge(prodH1, 6 * (sp + 1));  // h1(sp) complete
            spinge(prodH2, 6 * sp);        // h2(sp-1) complete
            const char* h1r = LDS + H1PAN + ((sp & 3) << 12);
            const char* h2r = LDS + H2PAN + (((sp - 1) & 3) << 12);
            f32x4 a[4];
            #pragma unroll
            for (int g = 0; g < 4; ++g) a[g] = (f32x4){bias[g], bias[g], bias[g], bias[g]};
            __builtin_amdgcn_s_setprio(1);
            #pragma unroll
            for (int j = 0; j < 6; ++j) {
                const char* pan = (j < 3) ? h1r : h2r;
                int cc = (j < 3) ? j : j - 3;
                int off = l15 * 256 + (((cc * 4 + kg) ^ r7) << 4);
                f16x8 ah = *(const f16x8*)(pan + off);
                #pragma unroll
                for (int g = 0; g < 4; ++g) a[g] = MFMA16(ah, F1[g][j], a[g]);
            }
            __builtin_amdgcn_s_setprio(0);
            signal(consH1, lane);          // h1(sp) consumed (reads drained by fence)
            // in-register EW (merged-rcp) -> h2(sp) slot sp&3
            char* h2w = LDS + H2PAN + ((sp & 3) << 12);
            #pragma unroll
            for (int q = 0; q < 4; ++q) {
                float ei = vexp2(a[0][q] * (-L2E));
                float ef = vexp2(a[1][q] * (-L2E));
                float eg = vexp2(a[2][q] * (-2.f * L2E));
                float eo = vexp2(a[3][q] * (-L2E));
                float ivgv = (1.f - eg) * vrcp((1.f + ei) * (1.f + eg));
                float fv = vrcp(1.f + ef);
                float cn = fmaf(fv, c2[q], ivgv);
                c2[q] = cn;
                float ec = vexp2(cn * (-2.f * L2E));
                float h = (1.f - ec) * vrcp((1.f + eo) * (1.f + ec));
                int r_ = kg * 4 + q;
                int off = r_ * 256 + ((cb ^ (r_ & 7)) << 4) + lo2;
                *(unsigned short*)(h2w + off) = f2h_bits(h);
                if (sp == TT - 1)
                    ((float*)(LDS + H2F32))[(ub * 16 + l15) * 16 + r_] = h;
            }
            signal(prodH2, lane);
        }
    }
    __syncthreads();

    // ---------------- MLP head on f32 h2(T-1): h2f[u*16 + r] ----------------
    const float* h2f = (const float*)(LDS + H2F32);
    float* z1 = (float*)(LDS + FCZ);          // [16][96]
    float* z2 = z1 + 1536;
    if (tid < 192) {
        int u = tid % 96, half = tid / 96;
        float s0 = fcb1[u];
        for (int r = half * 8; r < half * 8 + 8; ++r) {
            float s = s0;
            #pragma unroll 4
            for (int k = 0; k < 96; ++k) s += fcW1[u * 96 + k] * h2f[k * 16 + r];
            z1[r * 96 + u] = s > 0.f ? s : 0.01f * s;
        }
    }
    __syncthreads();
    if (tid < 192) {
        int u = tid % 96, half = tid / 96;
        float s0 = fcb2[u];
        for (int r = half * 8; r < half * 8 + 8; ++r) {
            float s = s0;
            #pragma unroll 4
            for (int k = 0; k < 96; ++k) s += fcW2[u * 96 + k] * z1[r * 96 + k];
            z2[r * 96 + u] = s > 0.f ? s : 0.01f * s;
        }
    }
    __syncthreads();
    if (tid < NB) {
        float s = fcb3[0];
        #pragma unroll 4
        for (int k = 0; k < 96; ++k) s += fcW3[k] * z2[tid * 96 + k];
        out[blk * NB + tid] = s;
    }
}

extern "C" void kernel_launch(void* const* d_in, const int* in_sizes, int n_in,
                              void* d_out, int out_size, void* d_ws, size_t ws_size,
                              hipStream_t stream) {
    const float* x    = (const float*)d_in[0];
    const float* Wih0 = (const float*)d_in[1];
    const float* Whh0 = (const float*)d_in[2];
    const float* b0   = (const float*)d_in[3];
    const float* Wih1 = (const float*)d_in[4];
    const float* Whh1 = (const float*)d_in[5];
    const float* b1   = (const float*)d_in[6];
    const float* fcW1 = (const float*)d_in[7];
    const float* fcb1 = (const float*)d_in[8];
    const float* fcW2 = (const float*)d_in[9];
    const float* fcb2 = (const float*)d_in[10];
    const float* fcW3 = (const float*)d_in[11];
    const float* fcb3 = (const float*)d_in[12];

    unsigned short* wsf2 = (unsigned short*)d_ws;   // 264 KB f16 fragment blocks

    prep_frags16<<<264, 512, 0, stream>>>(Wih0, Whh0, Wih1, Whh1, wsf2);
    lstm_main<<<256, NTHR, 0, stream>>>(x, b0, b1, fcW1, fcb1, fcW2, fcb2,
                                        fcW3, fcb3, wsf2, (float*)d_out);
}